// Round 8
// baseline (324.647 us; speedup 1.0000x reference)
//
#include <hip/hip_runtime.h>
#include <math.h>

#define NB 4
#define J 4096
#define KDIM 8192
#define DDIM 64
#define DD 64
#define TOPK 64

#define BM 32
#define THREADS 512
#define THREADS_SEL 256
#define NITER_H 8             // per half: 8 iters * (8 waves * 64 cols) = 4096 cols
#define CAP_H 128             // candidate capacity per row PER COLUMN-HALF
#define GCAP 256              // global candidate slots per row (2 halves)
#define OVFCAP 262144

// sharded route lists: group = 32 columns, shard = (b, group, pseudo-xcd)
#define KG 32
#define NKG (KDIM / KG)       // 256 groups per batch
#define NSHARD (NB * NKG * 8) // 8192
#define SHCAP 384             // 3x mean shard load; overflow -> ovf list
#define GW 4                  // waves per gather block

typedef _Float16 half8_t __attribute__((ext_vector_type(8)));
typedef float f32x16 __attribute__((ext_vector_type(16)));
union H8 { half8_t h; uint4 u; };
__device__ __forceinline__ half8_t as_h8(uint4 v) { H8 x; x.u = v; return x.h; }

__device__ __forceinline__ unsigned f2key(float f) {
  unsigned u = __float_as_uint(f);
  return u ^ (unsigned)(((int)u >> 31) | 0x80000000);
}
__device__ __forceinline__ float key2f(unsigned k) {
  unsigned u = (k & 0x80000000u) ? (k & 0x7FFFFFFFu) : ~k;
  return __uint_as_float(u);
}
__device__ __forceinline__ unsigned wred_maxu(unsigned v) {
  #pragma unroll
  for (int o = 32; o > 0; o >>= 1) { unsigned u = __shfl_xor(v, o, 64); v = u > v ? u : v; }
  return v;
}
__device__ __forceinline__ unsigned wred_minu(unsigned v) {
  #pragma unroll
  for (int o = 32; o > 0; o >>= 1) { unsigned u = __shfl_xor(v, o, 64); v = u < v ? u : v; }
  return v;
}
__device__ __forceinline__ float wred_addf(float v) {
  #pragma unroll
  for (int o = 32; o > 0; o >>= 1) v += __shfl_xor(v, o, 64);
  return v;
}

// append one route (b,k <- j, w) into its (group, xcd) shard list.
// Consecutive slots of a shard are consecutive addresses written by one
// pseudo-XCD -> tail line merges in that XCD's L2 (R7 lesson: per-(b,k)
// bucket scatter amplified 8B appends to 64B HBM lines = 64MB writes).
__device__ __forceinline__ void route_append(
    unsigned* shcnt, uint2* shlist, unsigned* ovf_cnt, uint2* ovf,
    int b, int xcd, unsigned kk, unsigned jloc, float w)
{
  const unsigned g = (unsigned)b * NKG + (kk >> 5);   // KG = 32
  const unsigned shard = (g << 3) | (unsigned)xcd;
  const unsigned slot = atomicAdd(&shcnt[shard], 1u);
  if (slot < SHCAP) {
    shlist[(size_t)shard * SHCAP + slot] =
        make_uint2(__float_as_uint(w), ((kk & (KG - 1)) << 12) | jloc);
  } else {
    const unsigned op = atomicAdd(ovf_cnt, 1u);
    if (op < (unsigned)OVFCAP)
      ovf[op] = make_uint2(__float_as_uint(w),
                           (((unsigned)b * KDIM + kk) << 12) | jloc);
  }
}

// ---------------------------------------------------------------------------
// K0: W_route -> f16 B-fragments (WFh) + fp32 transpose (WT, k-major).
// ---------------------------------------------------------------------------
__global__ void k_prep(const float* __restrict__ W, unsigned* __restrict__ WFh,
                       float* __restrict__ WT)
{
  __shared__ _Float16 lh[64][64];  // [col][d]
  __shared__ float lf[64][64];
  const int t = threadIdx.x;
  const int kb = blockIdx.x * 64;
  for (int i = t; i < 4096; i += 256) {
    const int d = i >> 6, c = i & 63;
    const float x = W[(size_t)d * KDIM + kb + c];
    lh[c][d] = (_Float16)x;
    lf[c][d] = x;
  }
  __syncthreads();
  for (int q = t; q < 512; q += 256) {
    const int gt2 = q >> 8, rem = q & 255;
    const int ks = rem >> 6, lane = rem & 63;
    const int c = gt2 * 32 + (lane & 31);
    const int d0 = ks * 16 + (lane >> 5) * 8;
    const int gtile = blockIdx.x * 2 + gt2;
    const size_t off = ((size_t)(gtile * 4 + ks) * 64 + lane) * 4;  // dwords
    *(uint4*)(WFh + off) = *(const uint4*)&lh[c][d0];
  }
  for (int q = t; q < 1024; q += 256) {
    const int c = q >> 4, d0 = (q & 15) * 4;
    *(float4*)(WT + (size_t)(kb + c) * DDIM + d0) = *(const float4*)&lf[c][d0];
  }
}

// ---------------------------------------------------------------------------
// K1a: fast pass, split over column halves (blockIdx.y = h in {0,1}).
// launch_bounds min-waves MUST stay at 4 (R2/R3: higher forces spill).
// ---------------------------------------------------------------------------
__global__ __launch_bounds__(THREADS, 4) void k_cand(
    const float* __restrict__ val, const unsigned* __restrict__ WFh,
    const float* __restrict__ W_val, float* __restrict__ pv,
    unsigned short* __restrict__ gidx, unsigned* __restrict__ gcnt,
    float* __restrict__ gtau, unsigned* __restrict__ flags)
{
  __shared__ __align__(16) float val_lds[BM][DDIM + 4];
  __shared__ unsigned short cand_idx[BM][CAP_H];
  __shared__ unsigned have[BM];
  __shared__ float tauF[BM];

  const int t = threadIdx.x;
  const int lane = t & 63;
  const int wv = t >> 6;                // 0..7
  const int hi = lane >> 5;
  const int lane31 = lane & 31;
  const int row0 = blockIdx.x * BM;
  const int h = blockIdx.y;             // column half

  {  // stage val rows (coalesced float4)
    const int r = t >> 4, d0 = (t & 15) * 4;
    const float4 v4 = *(const float4*)(val + (size_t)(row0 + r) * DDIM + d0);
    val_lds[r][d0] = v4.x; val_lds[r][d0 + 1] = v4.y;
    val_lds[r][d0 + 2] = v4.z; val_lds[r][d0 + 3] = v4.w;
  }
  __syncthreads();

  // tau (margined): logits | val_row ~ iid N(0, sigma^2), sigma = ||val||/8.
  if (t < BM) {
    float n2 = 0.f;
    #pragma unroll
    for (int d = 0; d < DDIM; ++d) { const float x = val_lds[t][d]; n2 = fmaf(x, x, n2); }
    tauF[t] = 0.26f * sqrtf(n2);  // 2.08/8 * ||val||
    have[t] = 0u;
    if (h == 0) gtau[row0 + t] = tauF[t];
  }

  // A fragments (f16)
  half8_t ah[4];
  {
    const int m = lane31;
    #pragma unroll
    for (int ks = 0; ks < 4; ++ks) {
      const int d0 = ks * 16 + hi * 8;
      #pragma unroll
      for (int j = 0; j < 8; ++j) ah[ks][j] = (_Float16)val_lds[m][d0 + j];
    }
  }
  __syncthreads();  // tau ready

  float taufr[16];
  #pragma unroll
  for (int r = 0; r < 16; ++r) taufr[r] = tauF[(r & 3) + 8 * (r >> 2) + 4 * hi];

  // ============== FAST PASS: pipelined loads, no barriers ==================
  const unsigned* wpBase = WFh + (size_t)(h * 128 + wv * 2) * 1024 + lane * 4;  // dwords
  const unsigned* wp = wpBase;
  uint4 b0 = *(const uint4*)(wp);        uint4 b1 = *(const uint4*)(wp + 256);
  uint4 b2 = *(const uint4*)(wp + 512);  uint4 b3 = *(const uint4*)(wp + 768);
  uint4 b4 = *(const uint4*)(wp + 1024); uint4 b5 = *(const uint4*)(wp + 1280);
  uint4 b6 = *(const uint4*)(wp + 1536); uint4 b7 = *(const uint4*)(wp + 1792);

  #pragma unroll 1
  for (int it = 0; it < NITER_H; ++it) {
    f32x16 acc0, acc1;
    #pragma unroll
    for (int i = 0; i < 16; ++i) { acc0[i] = 0.f; acc1[i] = 0.f; }
    acc0 = __builtin_amdgcn_mfma_f32_32x32x16_f16(ah[0], as_h8(b0), acc0, 0, 0, 0);
    acc1 = __builtin_amdgcn_mfma_f32_32x32x16_f16(ah[0], as_h8(b4), acc1, 0, 0, 0);
    acc0 = __builtin_amdgcn_mfma_f32_32x32x16_f16(ah[1], as_h8(b1), acc0, 0, 0, 0);
    acc1 = __builtin_amdgcn_mfma_f32_32x32x16_f16(ah[1], as_h8(b5), acc1, 0, 0, 0);
    acc0 = __builtin_amdgcn_mfma_f32_32x32x16_f16(ah[2], as_h8(b2), acc0, 0, 0, 0);
    acc1 = __builtin_amdgcn_mfma_f32_32x32x16_f16(ah[2], as_h8(b6), acc1, 0, 0, 0);
    acc0 = __builtin_amdgcn_mfma_f32_32x32x16_f16(ah[3], as_h8(b3), acc0, 0, 0, 0);
    acc1 = __builtin_amdgcn_mfma_f32_32x32x16_f16(ah[3], as_h8(b7), acc1, 0, 0, 0);

    const unsigned colbase = (unsigned)((h * 128 + it * 16 + wv * 2) * 32 + lane31);

    wp = (it == NITER_H - 1) ? wpBase : wp + 16384;
    b0 = *(const uint4*)(wp);        b1 = *(const uint4*)(wp + 256);
    b2 = *(const uint4*)(wp + 512);  b3 = *(const uint4*)(wp + 768);
    b4 = *(const uint4*)(wp + 1024); b5 = *(const uint4*)(wp + 1280);
    b6 = *(const uint4*)(wp + 1536); b7 = *(const uint4*)(wp + 1792);

    #pragma unroll
    for (int r = 0; r < 16; ++r) {
      const int row = (r & 3) + 8 * (r >> 2) + 4 * hi;
      const float tf = taufr[r];
      if (acc0[r] > tf) {
        const unsigned slot = atomicAdd(&have[row], 1u);
        if (slot < CAP_H) cand_idx[row][slot] = (unsigned short)colbase;
      }
      if (acc1[r] > tf) {
        const unsigned slot = atomicAdd(&have[row], 1u);
        if (slot < CAP_H) cand_idx[row][slot] = (unsigned short)(colbase + 32);
      }
    }
  }

  // ---- pv = val @ W_val ---- (h==1 blocks only)
  if (h == 1) {
    const int r = t >> 4, e0 = (t & 15) * 4;
    float a0 = 0.f, a1 = 0.f, a2 = 0.f, a3 = 0.f;
    #pragma unroll 8
    for (int d = 0; d < DDIM; ++d) {
      const float v = val_lds[r][d];
      const float4 w4 = *(const float4*)(W_val + (size_t)d * DD + e0);
      a0 = fmaf(v, w4.x, a0); a1 = fmaf(v, w4.y, a1);
      a2 = fmaf(v, w4.z, a2); a3 = fmaf(v, w4.w, a3);
    }
    *(float4*)(pv + (size_t)(row0 + r) * DD + e0) = make_float4(a0, a1, a2, a3);
  }

  __syncthreads();  // have[] + cand_idx final

  // ---- flush candidates to global (coalesced u16 runs per row) ----
  for (int i = t; i < BM * CAP_H; i += THREADS) {
    const int r = i >> 7, s = i & (CAP_H - 1);
    const unsigned hv = have[r];
    const int lim = hv < CAP_H ? (int)hv : CAP_H;
    if (s < lim)
      gidx[(size_t)(row0 + r) * GCAP + h * CAP_H + s] = cand_idx[r][s];
  }
  if (t < BM) {
    const unsigned hv = have[t];
    gcnt[(size_t)(row0 + t) * 2 + h] = hv < CAP_H ? hv : CAP_H;
    if (hv > CAP_H) flags[row0 + t] = 1u;  // incomplete -> k_fix
  }
}

// ---------------------------------------------------------------------------
// K1b: per-row selection, one wave per row. ILP-2 exact recompute (R7),
// ballot binary-search top-64, softmax, sharded route_append.
// ---------------------------------------------------------------------------
__global__ __launch_bounds__(THREADS_SEL, 4) void k_select(
    const float* __restrict__ val, const float* __restrict__ state,
    const float* __restrict__ WT,
    const unsigned short* __restrict__ gidx, const unsigned* __restrict__ gcnt,
    const float* __restrict__ gtau, unsigned* __restrict__ flags,
    unsigned* __restrict__ shcnt, uint2* __restrict__ shlist,
    unsigned* __restrict__ ovf_cnt, uint2* __restrict__ ovf)
{
  __shared__ float skey[THREADS_SEL / 64][GCAP];  // per-wave exact-key scratch
  const int t = threadIdx.x;
  const int lane = t & 63;
  const int wv = t >> 6;
  const int row = blockIdx.x * (THREADS_SEL / 64) + wv;
  const int xcd = blockIdx.x & 7;   // round-robin dispatch heuristic

  if (flags[row]) return;                 // incomplete candidates -> k_fix
  const int c0 = (int)gcnt[(size_t)row * 2];
  const int c1 = (int)gcnt[(size_t)row * 2 + 1];
  const int nc = c0 + c1;
  if (nc < TOPK) { if (lane == 0) flags[row] = 1u; return; }
  const float tau = gtau[row];

  // ---- exact fp32 keys: quad-cooperative, line-cooperative, ILP-2 ----
  const int cq = lane >> 2;   // candidate sub-slot within group: 0..15
  const int dq = lane & 3;    // quad sub-lane: 16B segment within each line
  float4 v4[4];
  #pragma unroll
  for (int j = 0; j < 4; ++j)
    v4[j] = *(const float4*)(val + (size_t)row * DDIM + j * 16 + dq * 4);

  const unsigned short* grow = gidx + (size_t)row * GCAP;

  unsigned id4[4];
  #pragma unroll
  for (int i = 0; i < 4; ++i) {
    const int s = i * 64 + lane;
    id4[i] = 0xFFFFFFFFu;
    if (s < nc) {
      const int ps = s < c0 ? s : (s - c0 + CAP_H);
      id4[i] = (unsigned)grow[ps];
    }
  }

  for (int s0 = 0; s0 < nc; s0 += 32) {
    const int sA = s0 + cq;
    const int sB = s0 + 16 + cq;
    const bool okA = sA < nc, okB = sB < nc;
    int psA = sA < c0 ? sA : (sA - c0 + CAP_H); if (!okA) psA = 0;
    int psB = sB < c0 ? sB : (sB - c0 + CAP_H); if (!okB) psB = 0;
    const unsigned kkA = (unsigned)grow[psA] & (KDIM - 1);
    const unsigned kkB = (unsigned)grow[psB] & (KDIM - 1);
    const float* wtA = WT + (size_t)kkA * DDIM + dq * 4;
    const float* wtB = WT + (size_t)kkB * DDIM + dq * 4;
    float4 wA[4], wB[4];
    #pragma unroll
    for (int j = 0; j < 4; ++j) wA[j] = *(const float4*)(wtA + j * 16);
    #pragma unroll
    for (int j = 0; j < 4; ++j) wB[j] = *(const float4*)(wtB + j * 16);
    float aA = 0.f, aB = 0.f;
    #pragma unroll
    for (int j = 0; j < 4; ++j) {
      aA = fmaf(v4[j].x, wA[j].x, aA); aA = fmaf(v4[j].y, wA[j].y, aA);
      aA = fmaf(v4[j].z, wA[j].z, aA); aA = fmaf(v4[j].w, wA[j].w, aA);
      aB = fmaf(v4[j].x, wB[j].x, aB); aB = fmaf(v4[j].y, wB[j].y, aB);
      aB = fmaf(v4[j].z, wB[j].z, aB); aB = fmaf(v4[j].w, wB[j].w, aB);
    }
    aA += __shfl_xor(aA, 1, 64); aA += __shfl_xor(aA, 2, 64);
    aB += __shfl_xor(aB, 1, 64); aB += __shfl_xor(aB, 2, 64);
    if (dq == 0) {
      if (okA) skey[wv][sA] = aA;
      if (okB) skey[wv][sB] = aB;
    }
  }
  asm volatile("s_waitcnt lgkmcnt(0)" ::: "memory");
  __builtin_amdgcn_sched_barrier(0);

  // ---- top-64 via ballot binary search, softmax, append ----
  unsigned k4[4];
  #pragma unroll
  for (int i = 0; i < 4; ++i) {
    const int s = i * 64 + lane;
    k4[i] = (s < nc) ? f2key(skey[wv][s]) : 0u;
  }
  unsigned lmax = k4[0];
  #pragma unroll
  for (int i = 1; i < 4; ++i) lmax = k4[i] > lmax ? k4[i] : lmax;
  const unsigned kmaxAll = wred_maxu(lmax);
  unsigned klo = f2key(0.99f * tau); if (klo == 0u) klo = 1u;
  unsigned khi = kmaxAll + 1u;
  auto cge4 = [&](unsigned th) {
    int c = 0;
    #pragma unroll
    for (int i = 0; i < 4; ++i) c += __popcll(__ballot(k4[i] >= th));
    return c;
  };
  int cnt = nc;
  while (cnt != TOPK && khi - klo > 1u) {
    const unsigned mid = klo + ((khi - klo) >> 1);
    const int c = cge4(mid);
    if (c >= TOPK) { klo = mid; cnt = c; } else khi = mid;
  }
  const unsigned thr = klo;
  if (key2f(thr) <= 1.006f * tau) {   // completeness certificate
    if (lane == 0) flags[row] = 1u;
    return;
  }
  unsigned selmask = 0u;
  if (cnt == TOPK) {
    #pragma unroll
    for (int i = 0; i < 4; ++i) if (k4[i] >= thr) selmask |= 1u << i;
  } else {
    #pragma unroll
    for (int i = 0; i < 4; ++i) if (k4[i] > thr) selmask |= 1u << i;
    int tot = 0;
    #pragma unroll
    for (int i = 0; i < 4; ++i) tot += __popcll(__ballot((selmask >> i) & 1));
    int need = TOPK - tot;
    while (need > 0) {
      unsigned best = 0xFFFFFFFFu; int bi = -1;
      #pragma unroll
      for (int i = 0; i < 4; ++i)
        if (k4[i] == thr && !(selmask & (1u << i)) && id4[i] < best) { best = id4[i]; bi = i; }
      const unsigned g = wred_minu(best);
      if (g == 0xFFFFFFFFu) break;
      if (bi >= 0 && best == g) selmask |= 1u << bi;
      --need;
    }
  }
  const float m = key2f(kmaxAll);
  float p[4]; float lsum = 0.f;
  #pragma unroll
  for (int i = 0; i < 4; ++i) {
    p[i] = 0.f;
    if (selmask & (1u << i)) { p[i] = __expf(key2f(k4[i]) - m); lsum += p[i]; }
  }
  lsum = wred_addf(lsum);
  const float st = state[row];
  const float sender = st > 20.f ? st : log1pf(__expf(st));
  const float scale = sender / lsum;
  const int b = row / J;
  const unsigned jloc = (unsigned)(row & (J - 1));
  #pragma unroll
  for (int i = 0; i < 4; ++i) {
    if (selmask & (1u << i))
      route_append(shcnt, shlist, ovf_cnt, ovf, b, xcd, id4[i], jloc, p[i] * scale);
  }
}

// ---------------------------------------------------------------------------
// K2: exactness net for flagged rows (rare; early-exits fast).
// ---------------------------------------------------------------------------
__global__ void k_fix(const float* __restrict__ val, const float* __restrict__ state,
                      const float* __restrict__ W, const unsigned* __restrict__ flags,
                      unsigned* __restrict__ shcnt, uint2* __restrict__ shlist,
                      unsigned* __restrict__ ovf_cnt, uint2* __restrict__ ovf)
{
  __shared__ unsigned anyf;
  __shared__ unsigned lsk[64][TOPK + 1];
  __shared__ unsigned short lsi[64][TOPK];
  const int t = threadIdx.x;
  const int row = blockIdx.x * 64 + t;
  const int xcd = blockIdx.x & 7;
  if (t == 0) anyf = 0u;
  __syncthreads();
  const unsigned f = flags[row];
  if (f) anyf = 1u;
  __syncthreads();
  if (!anyf) return;
  if (!f) return;

  float v[DDIM];
  #pragma unroll
  for (int d = 0; d < DDIM; ++d) v[d] = val[(size_t)row * DDIM + d];
  int m = 0, worst = 0;
  for (int k = 0; k < KDIM; ++k) {
    float acc = 0.f;
    #pragma unroll 8
    for (int d = 0; d < DDIM; ++d) acc = fmaf(v[d], W[(size_t)d * KDIM + k], acc);
    const unsigned key = f2key(acc);
    if (m < TOPK) {
      lsk[t][m] = key; lsi[t][m] = (unsigned short)k; ++m;
      if (m == TOPK) {
        worst = 0;
        for (int q = 1; q < TOPK; ++q)
          if (lsk[t][q] < lsk[t][worst] ||
              (lsk[t][q] == lsk[t][worst] && lsi[t][q] > lsi[t][worst])) worst = q;
      }
    } else if (key > lsk[t][worst]) {
      lsk[t][worst] = key; lsi[t][worst] = (unsigned short)k;
      worst = 0;
      for (int q = 1; q < TOPK; ++q)
        if (lsk[t][q] < lsk[t][worst] ||
            (lsk[t][q] == lsk[t][worst] && lsi[t][q] > lsi[t][worst])) worst = q;
    }
  }
  unsigned km = lsk[t][0];
  for (int q = 1; q < TOPK; ++q) if (lsk[t][q] > km) km = lsk[t][q];
  const float mx = key2f(km);
  float lsum = 0.f;
  for (int q = 0; q < TOPK; ++q) lsum += __expf(key2f(lsk[t][q]) - mx);
  const float st = state[row];
  const float sender = st > 20.f ? st : log1pf(__expf(st));
  const float scale = sender / lsum;
  const int b = row / J;
  const unsigned jloc = (unsigned)(row & (J - 1));
  for (int q = 0; q < TOPK; ++q) {
    const float w = __expf(key2f(lsk[t][q]) - mx) * scale;
    route_append(shcnt, shlist, ovf_cnt, ovf, b, xcd, (unsigned)lsi[t][q], jloc, w);
  }
}

// ---------------------------------------------------------------------------
// K3: gather. Block owns (b, 32-column group); reads its 8 shards densely,
// accumulates w*pv[j] into per-wave LDS replicas (65th column = state sum),
// merges, adds dst, stores. No atomics, dense reads/writes.
// ---------------------------------------------------------------------------
__global__ __launch_bounds__(256, 4) void k_gather(
    const unsigned* __restrict__ shcnt, const uint2* __restrict__ shlist,
    const float* __restrict__ pv, const float* __restrict__ state,
    const float* __restrict__ dst_state, const float* __restrict__ dst_val,
    float* __restrict__ out_state, float* __restrict__ out_val)
{
  __shared__ float accv[GW][KG][DD + 1];   // [wave][k_local][d] ; d==DD holds state sum
  const int t = threadIdx.x;
  const int lane = t & 63;
  const int wv = t >> 6;
  const int b  = blockIdx.x >> 8;          // NKG = 256
  const int kg = blockIdx.x & (NKG - 1);
  const size_t jbase = (size_t)b * J;

  for (int i = t; i < GW * KG * (DD + 1); i += 256) ((float*)accv)[i] = 0.f;
  __syncthreads();

  const int gbase = (b * NKG + kg) << 3;
  for (int x = 0; x < 8; ++x) {
    const unsigned n0 = shcnt[gbase + x];
    const unsigned n = n0 < SHCAP ? n0 : SHCAP;
    const uint2* lst = shlist + (size_t)(gbase + x) * SHCAP;
    for (unsigned base = (unsigned)wv * 64; base < n; base += GW * 64) {
      const uint2 e = lst[base + lane];          // safe: within workspace
      const int mrem = (int)(n - base);
      const int mm = mrem < 64 ? mrem : 64;
      // this lane's own entry's state contribution source
      const float sOwn = (lane < mm) ? state[jbase + (e.y & (J - 1))] : 0.f;
      for (int c0 = 0; c0 < mm; c0 += 8) {
        float pw[8], vv[8], sv[8]; int kk[8], ok[8];
        #pragma unroll
        for (int i = 0; i < 8; ++i) {
          const int c = (c0 + i) & 63;
          const unsigned ex = __shfl(e.x, c, 64);
          const unsigned ey = __shfl(e.y, c, 64);
          ok[i] = (c0 + i) < mm;
          pw[i] = __uint_as_float(ex);
          kk[i] = (int)((ey >> 12) & (KG - 1));
          const unsigned j = ey & (J - 1);
          vv[i] = ok[i] ? pv[(jbase + j) * DD + lane] : 0.f;
          sv[i] = __shfl(sOwn, c, 64);
        }
        #pragma unroll
        for (int i = 0; i < 8; ++i) {
          if (ok[i]) {
            accv[wv][kk[i]][lane] += pw[i] * vv[i];
            if (lane == 0) accv[wv][kk[i]][DD] += pw[i] * sv[i];
          }
        }
      }
    }
  }
  __syncthreads();

  // merge replicas + add dst + store (coalesced)
  const int k0 = kg * KG;
  for (int i = t; i < KG * DD; i += 256) {
    const int k = i >> 6, d = i & 63;
    const float s = ((accv[0][k][d] + accv[1][k][d]) +
                     (accv[2][k][d] + accv[3][k][d]));
    const size_t o = ((size_t)b * KDIM + k0 + k) * DD + d;
    out_val[o] = dst_val[o] + s;
  }
  if (t < KG) {
    const float s = ((accv[0][t][DD] + accv[1][t][DD]) +
                     (accv[2][t][DD] + accv[3][t][DD]));
    const size_t o = (size_t)b * KDIM + k0 + t;
    out_state[o] = dst_state[o] + s;
  }
}

// ---------------------------------------------------------------------------
// K4: fold overflow-list routes into outputs (runs AFTER k_gather).
// ---------------------------------------------------------------------------
__global__ void k_ovf(const unsigned* __restrict__ ovf_cnt, const uint2* __restrict__ ovf,
                      const float* __restrict__ pv, const float* __restrict__ state,
                      float* __restrict__ out_state, float* __restrict__ out_val)
{
  unsigned n = *ovf_cnt;
  if (n > (unsigned)OVFCAP) n = (unsigned)OVFCAP;
  const unsigned wglob = (blockIdx.x * blockDim.x + threadIdx.x) >> 6;
  const int lane = threadIdx.x & 63;
  const unsigned nw = (gridDim.x * blockDim.x) >> 6;
  for (unsigned i = wglob; i < n; i += nw) {
    const uint2 e = ovf[i];
    const float w = __uint_as_float(e.x);
    const unsigned bk = e.y >> 12;
    const unsigned j = e.y & (J - 1);
    const size_t jg = (size_t)(bk >> 13) * J + j;
    atomicAdd(&out_val[(size_t)bk * DD + lane], w * pv[jg * DD + lane]);
    if (lane == 0) atomicAdd(&out_state[bk], w * state[jg]);
  }
}

// ---------------------------------------------------------------------------
extern "C" void kernel_launch(void* const* d_in, const int* in_sizes, int n_in,
                              void* d_out, int out_size, void* d_ws, size_t ws_size,
                              hipStream_t stream)
{
  (void)in_sizes; (void)n_in; (void)out_size; (void)ws_size;
  const float* val       = (const float*)d_in[0];
  const float* state     = (const float*)d_in[1];
  const float* dst_state = (const float*)d_in[2];
  const float* dst_val   = (const float*)d_in[3];
  const float* W_route   = (const float*)d_in[4];
  const float* W_val     = (const float*)d_in[5];
  float* out_state = (float*)d_out;
  float* out_val   = out_state + (size_t)NB * KDIM;

  char* p = (char*)d_ws;
  unsigned* shcnt   = (unsigned*)p;  p += (size_t)NSHARD * 4;          // 32 KB
  unsigned* flags   = (unsigned*)p;  p += (size_t)NB * J * 4;          // 64 KB
  unsigned* ovf_cnt = (unsigned*)p;  p += 256;                         // 256 B
  unsigned* gcnt    = (unsigned*)p;  p += (size_t)NB * J * 2 * 4;      // 128 KB
  float* pv         = (float*)p;     p += (size_t)NB * J * DD * 4;     // 4 MB
  unsigned* WFh     = (unsigned*)p;  p += (size_t)KDIM * DDIM * 2;     // 1 MB
  float* WT         = (float*)p;     p += (size_t)KDIM * DDIM * 4;     // 2 MB
  float* gtau       = (float*)p;     p += (size_t)NB * J * 4;          // 64 KB
  unsigned short* gidx = (unsigned short*)p; p += (size_t)NB * J * GCAP * 2; // 8 MB
  uint2* shlist     = (uint2*)p;     p += (size_t)NSHARD * SHCAP * 8;  // 24 MB
  uint2* ovf        = (uint2*)p;     p += (size_t)OVFCAP * 8;          // 2 MB

  // zero shcnt + flags + ovf_cnt + gcnt (contiguous)
  hipMemsetAsync(shcnt, 0,
                 (size_t)NSHARD * 4 + (size_t)NB * J * 4 + 256 +
                 (size_t)NB * J * 2 * 4, stream);

  hipLaunchKernelGGL(k_prep, dim3(KDIM / 64), dim3(256), 0, stream, W_route, WFh, WT);
  hipLaunchKernelGGL(k_cand, dim3(NB * J / BM, 2), dim3(THREADS), 0, stream,
                     val, WFh, W_val, pv, gidx, gcnt, gtau, flags);
  hipLaunchKernelGGL(k_select, dim3(NB * J / (THREADS_SEL / 64)), dim3(THREADS_SEL),
                     0, stream, val, state, WT, gidx, gcnt, gtau, flags,
                     shcnt, shlist, ovf_cnt, ovf);
  hipLaunchKernelGGL(k_fix, dim3(NB * J / 64), dim3(64), 0, stream,
                     val, state, W_route, flags, shcnt, shlist, ovf_cnt, ovf);
  hipLaunchKernelGGL(k_gather, dim3(NB * NKG), dim3(256), 0, stream,
                     shcnt, shlist, pv, state, dst_state, dst_val, out_state, out_val);
  hipLaunchKernelGGL(k_ovf, dim3(256), dim3(256), 0, stream,
                     ovf_cnt, ovf, pv, state, out_state, out_val);
}